// Round 4
// baseline (249.370 us; speedup 1.0000x reference)
//
#include <hip/hip_runtime.h>

#define BATCH   1024
#define MSIZE   65536
#define KDIM    256
#define CHOOSEK 128
#define SELK    160        // suffix-count crossing target; superset = SELK..SELK+bucket (~350-600)
#define BETA    1e-8f
#define ALPHA   0.5f
// linear u8 key: key = min(255, score*KSCALE). score <= exp(sim-1)*(histmax+beta);
// sims ~ N(0,1/16) => score <~ 6e-4 whp. KSCALE = 256/6e-4. ~330 items/bucket => byte-granular
// threshold yields ncand ~ [160, ~700] << 1024 cap. Monotone quantization keeps superset exact.
#define KSCALE  426666.7f

typedef short bf16x8 __attribute__((ext_vector_type(8)));
typedef float f32x4  __attribute__((ext_vector_type(4)));

__device__ inline unsigned int pack2bf(float a, float b) {   // RNE fp32->bf16 pair
    unsigned int ua = __float_as_uint(a);
    unsigned int ub = __float_as_uint(b);
    ua += 0x7fffu + ((ua >> 16) & 1u);
    ub += 0x7fffu + ((ub >> 16) & 1u);
    return (ua >> 16) | (ub & 0xffff0000u);
}

// async global->LDS, 16B/lane; LDS dest is wave-uniform base + lane*16 (must be linear in tid)
#define GLD16(g, l) __builtin_amdgcn_global_load_lds( \
    (const __attribute__((address_space(1))) unsigned int*)(g), \
    (__attribute__((address_space(3))) unsigned int*)(l), 16, 0, 0)

// -------------------------------------------------------------------------
// Kernel 0: one-time fp32 -> bf16 convert of q and key.
// -------------------------------------------------------------------------
__global__ __launch_bounds__(256)
void convert_kernel(const float* __restrict__ q, const float* __restrict__ key,
                    unsigned short* __restrict__ qb, unsigned short* __restrict__ kb)
{
    const int id = blockIdx.x * 256 + threadIdx.x;
    const float* src; unsigned short* dst; int off;
    if (blockIdx.x < 128) { src = q;   dst = qb; off = id; }
    else                  { src = key; dst = kb; off = id - 32768; }
    const float4* s4 = (const float4*)src;
    float4 a = s4[off * 2];
    float4 b = s4[off * 2 + 1];
    uint4 p = make_uint4(pack2bf(a.x, a.y), pack2bf(a.z, a.w),
                         pack2bf(b.x, b.y), pack2bf(b.z, b.w));
    ((uint4*)dst)[off] = p;
}

// -------------------------------------------------------------------------
// Kernel 1: bf16 screening GEMM, 128x128 tile, BK=32.
//  - B (key tile) double-buffered in LDS via global_load_lds (16 KB total).
//  - A (q tile) loaded straight from global (qb is 512 KB, L2-resident) into
//    VGPRs, double-buffered across K-steps -> no A staging, no A ds_reads.
//  - MFMA operands SWAPPED vs earlier rounds: acc[i][j] = mfma(kf[i], qf[j])
//    so D row = mem, col = batch. Lane's 4 regs = 4 consecutive mem slots of
//    ONE batch row -> epilogue packs 4 u8 keys into one dword store (16 stores
//    instead of 64 byte-stores), and hist loads become float4.
// Epilogue: u8 key = min(255, exp(sim-1)*(hist+beta)*KSCALE).
// -------------------------------------------------------------------------
__global__ __launch_bounds__(256)
void score_kernel(const unsigned short* __restrict__ qb,
                  const unsigned short* __restrict__ kb,
                  const float* __restrict__ hist,
                  unsigned char* __restrict__ s8)
{
    __shared__ __align__(16) unsigned short Bs[2][128 * 32];
    const int tid = threadIdx.x;
    const int bid = blockIdx.x;
    const int b0 = ((bid >> 3) & 7) * 128;                 // batch tile (8)
    const int n0 = ((bid & 7) + ((bid >> 6) << 3)) * 128;  // memory tile (512), XCD-grouped
    const int lane = tid & 63, wave = tid >> 6;
    const int wm = (wave >> 1) * 64, wn = (wave & 1) * 64;
    const int l15 = lane & 15, l4 = lane >> 4;

    f32x4 acc[4][4] = {};

    // B staging: 128 rows x 32 cols = 8 KB/step; 256 thr * 16B = 4 KB/GLD16 -> 2 per step
    const int srow = tid >> 2;          // 0..63
    const int seg  = (tid & 3) * 8;
    const unsigned short* gB = kb + (size_t)(n0 + srow) * KDIM + seg;
    const int lofs = srow * 32 + seg;   // byte offset tid*16: linear per wave

    // A fragments direct from global: q row = b0 + wm + j*16 + l15, col = ks*32 + l4*8
    const unsigned short* gq = qb + (size_t)(b0 + wm + l15) * KDIM + l4 * 8;

    bf16x8 qf[2][4];

    // prologue: stage B step 0, load q frags step 0
    GLD16(gB,             &Bs[0][lofs]);
    GLD16(gB + 64 * KDIM, &Bs[0][lofs + 64 * 32]);
#pragma unroll
    for (int j = 0; j < 4; ++j)
        qf[0][j] = *(const bf16x8*)(gq + j * 16 * KDIM);
    __syncthreads();                    // vmcnt(0) drained -> buf0 + qf[0] ready

#pragma unroll
    for (int ks = 0; ks < 8; ++ks) {
        const int cur = ks & 1;
        if (ks < 7) {                   // prefetch next K-step (overlaps MFMA below)
            const int nxt = cur ^ 1;
            const int ko  = (ks + 1) * 32;
#pragma unroll
            for (int j = 0; j < 4; ++j)
                qf[nxt][j] = *(const bf16x8*)(gq + j * 16 * KDIM + ko);
            GLD16(gB + ko,             &Bs[nxt][lofs]);
            GLD16(gB + ko + 64 * KDIM, &Bs[nxt][lofs + 64 * 32]);
        }
        bf16x8 kf[4];
#pragma unroll
        for (int i = 0; i < 4; ++i)
            kf[i] = *(const bf16x8*)(&Bs[cur][(wn + i * 16 + l15) * 32 + l4 * 8]);
#pragma unroll
        for (int i = 0; i < 4; ++i)
#pragma unroll
            for (int j = 0; j < 4; ++j)
                acc[i][j] = __builtin_amdgcn_mfma_f32_16x16x32_bf16(kf[i], qf[cur][j], acc[i][j], 0, 0, 0);
        __syncthreads();                // drains vmcnt (next bufs ready) + lgkmcnt (reads done)
    }

    // epilogue (swapped layout): within acc[i][j]:
    //   mem   = n0 + wn + i*16 + l4*4 + reg   (4 consecutive per lane)
    //   batch = b0 + wm + j*16 + l15
    float4 hj[4];
#pragma unroll
    for (int i = 0; i < 4; ++i) {
        float4 h = *(const float4*)&hist[n0 + wn + i * 16 + l4 * 4];
        hj[i] = make_float4((h.x + BETA) * KSCALE, (h.y + BETA) * KSCALE,
                            (h.z + BETA) * KSCALE, (h.w + BETA) * KSCALE);
    }
#pragma unroll
    for (int j = 0; j < 4; ++j) {
        const size_t row = (size_t)(b0 + wm + j * 16 + l15) * MSIZE;
#pragma unroll
        for (int i = 0; i < 4; ++i) {
            const float* hv = (const float*)&hj[i];
            unsigned int pk = 0;
#pragma unroll
            for (int reg = 0; reg < 4; ++reg) {
                float sc = __expf(acc[i][j][reg] - 1.0f) * hv[reg];
                pk |= (unsigned int)(unsigned char)(int)fminf(sc, 255.0f) << (8 * reg);
            }
            *(unsigned int*)(s8 + row + (n0 + wn + i * 16 + l4 * 4)) = pk;
        }
    }
}

// -------------------------------------------------------------------------
// Kernel 2: per batch row, latency-optimized (unchanged from round 3):
//   pass 1: histogram of bytes >= 128 only (word prescreen), exact fallback;
//   single-wave shfl suffix-scan; pass 2 prescreened collect; 16-lane-group
//   rescore; exact count-based top-128; weighted sum.
// -------------------------------------------------------------------------
__global__ __launch_bounds__(256, 4)
void select_kernel(const float* __restrict__ q,
                   const float* __restrict__ key,
                   const float* __restrict__ hist,
                   const float* __restrict__ vals,
                   const unsigned char* __restrict__ s8,
                   float* __restrict__ out)
{
    const int b   = blockIdx.x;
    const int tid = threadIdx.x;

    __shared__ __align__(16) float qs[KDIM];
    __shared__ unsigned int hcnt[16 * 257];   // 16 replicated histograms
    __shared__ int   stot[256];
    __shared__ int   scal[2];                 // 0:H  1:ncand
    __shared__ int   cidx[1024];
    __shared__ float csc[1024], cjj[1024], cjv[1024];
    __shared__ float wred[8];

    qs[tid] = q[(size_t)b * KDIM + tid];
    const uint4* rowp = reinterpret_cast<const uint4*>(s8 + (size_t)b * MSIZE);
    const int rep = (tid & 15) * 257;

    // ---- threshold search: prescreened histogram, exact fallback ----
    int H = -1;
    int minb = 128;
    for (;;) {
        for (int i = tid; i < 16 * 257; i += 256) hcnt[i] = 0u;
        if (tid == 0) { scal[0] = -1; scal[1] = 0; }
        __syncthreads();

        for (int i = 0; i < 16; ++i) {
            uint4 v = rowp[i * 256 + tid];
            unsigned int w[4] = {v.x, v.y, v.z, v.w};
#pragma unroll
            for (int k = 0; k < 4; ++k) {
                if (minb == 0 || (w[k] & 0x80808080u)) {
#pragma unroll
                    for (int jj = 0; jj < 4; ++jj) {
                        int bb = (int)((w[k] >> (8 * jj)) & 0xffu);
                        if (bb >= minb) atomicAdd(&hcnt[rep + bb], 1u);
                    }
                }
            }
        }
        __syncthreads();
        { unsigned int t = 0;
#pragma unroll
          for (int k = 0; k < 16; ++k) t += hcnt[k * 257 + tid];
          stot[tid] = (int)t; }
        __syncthreads();

        // single-wave suffix scan over 256 bins; find crossing S[b]>=SELK>S[b+1]
        if (tid < 64) {
            const int l = tid;
            int t0 = stot[l * 4], t1 = stot[l * 4 + 1], t2 = stot[l * 4 + 2], t3 = stot[l * 4 + 3];
            int lsum = t0 + t1 + t2 + t3;
            int s = lsum;
#pragma unroll
            for (int off = 1; off < 64; off <<= 1) {
                int u = __shfl_down(s, off, 64);
                if (l + off < 64) s += u;
            }
            int A  = s - lsum;        // sum over lanes > l (== S[4l+4])
            int S3 = A + t3;
            int S2 = S3 + t2;
            int S1 = S2 + t1;
            int S0 = S1 + t0;
            if (S0 >= SELK && S1 < SELK) scal[0] = l * 4 + 0;
            if (S1 >= SELK && S2 < SELK) scal[0] = l * 4 + 1;
            if (S2 >= SELK && S3 < SELK) scal[0] = l * 4 + 2;
            if (S3 >= SELK && A  < SELK) scal[0] = l * 4 + 3;
        }
        __syncthreads();
        H = scal[0];
        __syncthreads();              // all threads read H before next-iter rewrites
        if (H >= 0) break;
        minb = 0;                     // threshold below 128: exact full histogram
    }

    // ---- pass 2: collect candidates (byte >= H); row re-read hits L3 ----
    const unsigned int uH = (unsigned int)H;
    const bool pre = (H >= 128);
    for (int i = 0; i < 16; ++i) {
        uint4 v = rowp[i * 256 + tid];
        const int base = (i * 256 + tid) * 16;
        unsigned int w[4] = {v.x, v.y, v.z, v.w};
#pragma unroll
        for (int k = 0; k < 4; ++k) {
            if (!pre || (w[k] & 0x80808080u)) {
#pragma unroll
                for (int jj = 0; jj < 4; ++jj) {
                    unsigned int bb = (w[k] >> (8 * jj)) & 0xffu;
                    if (bb >= uH) {
                        int p = atomicAdd(&scal[1], 1);
                        if (p < 1024) cidx[p] = base + 4 * k + jj;
                    }
                }
            }
        }
    }
    __syncthreads();
    const int ncand = min(scal[1], 1024);

    // ---- exact fp32 rescore: 16-lane groups, 4 candidates per wave in flight ----
    const int gid = tid >> 4, gl = tid & 15;
    const float4* q4 = (const float4*)qs;
    for (int i = gid; i < ncand; i += 16) {
        const int idx = cidx[i];
        const float4* kp = (const float4*)(key + (size_t)idx * KDIM);
        float p = 0.f;
#pragma unroll
        for (int u = 0; u < 4; ++u) {
            float4 kk = kp[gl * 4 + u];
            float4 qq = q4[gl * 4 + u];
            p += kk.x * qq.x + kk.y * qq.y + kk.z * qq.z + kk.w * qq.w;
        }
#pragma unroll
        for (int off = 1; off < 16; off <<= 1) p += __shfl_xor(p, off, 64);
        if (gl == 0) {
            float e = expf(p - 1.0f);
            float h = hist[idx];
            csc[i] = e * (h + BETA);
            float j = e * (ALPHA * h + BETA);
            cjj[i] = j;
            cjv[i] = j * vals[idx];
        }
    }
    __syncthreads();

    // ---- exact top-128 among candidates (count-based; ties -> lower index) ----
    const int wave = tid >> 6, lane = tid & 63;
    float pn = 0.f, pd = 0.f;
    for (int i = tid; i < ncand; i += 256) {
        float si = csc[i]; int ii = cidx[i]; int rank = 0;
        for (int t = 0; t < ncand; ++t) {
            float st = csc[t];
            rank += (st > si || (st == si && cidx[t] < ii)) ? 1 : 0;
        }
        if (rank < CHOOSEK) { pn += cjv[i]; pd += cjj[i]; }
    }
#pragma unroll
    for (int off = 32; off > 0; off >>= 1) {
        pn += __shfl_xor(pn, off, 64);
        pd += __shfl_xor(pd, off, 64);
    }
    if (lane == 0) { wred[wave] = pn; wred[4 + wave] = pd; }
    __syncthreads();
    if (tid == 0) {
        float n = wred[0] + wred[1] + wred[2] + wred[3];
        float d = wred[4] + wred[5] + wred[6] + wred[7];
        out[b] = n / d;
    }
}

// -------------------------------------------------------------------------
extern "C" void kernel_launch(void* const* d_in, const int* in_sizes, int n_in,
                              void* d_out, int out_size, void* d_ws, size_t ws_size,
                              hipStream_t stream)
{
    (void)in_sizes; (void)n_in; (void)out_size; (void)ws_size;
    const float* q    = (const float*)d_in[0];
    const float* key  = (const float*)d_in[1];
    const float* hist = (const float*)d_in[2];
    const float* vals = (const float*)d_in[3];
    float* out = (float*)d_out;

    // workspace layout (96.5 MiB total):
    unsigned char*  s8 = (unsigned char*)d_ws;                                  // 64 MiB u8 keys
    unsigned short* kb = (unsigned short*)((char*)d_ws + ((size_t)64 << 20));   // 32 MiB bf16 key
    unsigned short* qb = (unsigned short*)((char*)d_ws + ((size_t)96 << 20));   // 512 KiB bf16 q

    convert_kernel<<<8320, 256, 0, stream>>>(q, key, qb, kb);
    score_kernel<<<4096, 256, 0, stream>>>(qb, kb, hist, s8);
    select_kernel<<<BATCH, 256, 0, stream>>>(q, key, hist, vals, s8, out);
}

// Round 5
// 224.057 us; speedup vs baseline: 1.1130x; 1.1130x over previous
//
#include <hip/hip_runtime.h>

#define BATCH   1024
#define MSIZE   65536
#define KDIM    256
#define CHOOSEK 128
#define SELK    160        // suffix-count crossing target; superset = SELK..SELK+bucket (~350-600)
#define BETA    1e-8f
#define ALPHA   0.5f
// linear u8 key: key = min(255, score*KSCALE). score <= exp(sim-1)*(histmax+beta);
// sims ~ N(0,1/16) => score <~ 6e-4 whp. KSCALE = 256/6e-4. ~330 items/bucket => byte-granular
// threshold yields ncand ~ [160, ~700] << 1024 cap. Monotone quantization keeps superset exact.
#define KSCALE  426666.7f

typedef short bf16x8 __attribute__((ext_vector_type(8)));
typedef float f32x4  __attribute__((ext_vector_type(4)));

__device__ inline unsigned int pack2bf(float a, float b) {   // RNE fp32->bf16 pair
    unsigned int ua = __float_as_uint(a);
    unsigned int ub = __float_as_uint(b);
    ua += 0x7fffu + ((ua >> 16) & 1u);
    ub += 0x7fffu + ((ub >> 16) & 1u);
    return (ua >> 16) | (ub & 0xffff0000u);
}

// async global->LDS, 16B/lane; LDS dest is wave-uniform base + lane*16 (must be linear in tid)
#define GLD16(g, l) __builtin_amdgcn_global_load_lds( \
    (const __attribute__((address_space(1))) unsigned int*)(g), \
    (__attribute__((address_space(3))) unsigned int*)(l), 16, 0, 0)

// -------------------------------------------------------------------------
// Kernel 0: one-time fp32 -> bf16 convert of q and key.
// -------------------------------------------------------------------------
__global__ __launch_bounds__(256)
void convert_kernel(const float* __restrict__ q, const float* __restrict__ key,
                    unsigned short* __restrict__ qb, unsigned short* __restrict__ kb)
{
    const int id = blockIdx.x * 256 + threadIdx.x;
    const float* src; unsigned short* dst; int off;
    if (blockIdx.x < 128) { src = q;   dst = qb; off = id; }
    else                  { src = key; dst = kb; off = id - 32768; }
    const float4* s4 = (const float4*)src;
    float4 a = s4[off * 2];
    float4 b = s4[off * 2 + 1];
    uint4 p = make_uint4(pack2bf(a.x, a.y), pack2bf(a.z, a.w),
                         pack2bf(b.x, b.y), pack2bf(b.z, b.w));
    ((uint4*)dst)[off] = p;
}

// -------------------------------------------------------------------------
// Kernel 1: bf16 screening GEMM, 128x128 tile, BK=32, K=256 -> 8 stages.
// T4 counted-vmcnt pipeline: 4-buffer LDS ring (64 KB), prefetch depth 2,
// ONE raw s_barrier per step, vmcnt(8) in steady state (never 0 mid-loop).
// Ring safety: buffer (s+3)&3 written at step s was last read at step s-1;
// all waves' step-(s-1) ds_reads completed (lgkm-waited before their MFMAs)
// before they reach step-s's barrier.
// Both A(q) and B(key) staged via global_load_lds (round-4 reg-staging of A
// regressed: 16 scattered 64B loads/wave lengthened the drain).
// MFMA swapped: acc[i][j] = mfma(kf[i], qf[j]) -> lane's 4 regs = 4 consecutive
// mem slots of one batch row -> epilogue packs 4 u8 into one dword store.
// -------------------------------------------------------------------------
__global__ __launch_bounds__(256)
void score_kernel(const unsigned short* __restrict__ qb,
                  const unsigned short* __restrict__ kb,
                  const float* __restrict__ hist,
                  unsigned char* __restrict__ s8)
{
    __shared__ __align__(16) unsigned short As[4][128 * 32];   // 4 x 8 KB
    __shared__ __align__(16) unsigned short Bs[4][128 * 32];   // 4 x 8 KB
    const int tid = threadIdx.x;
    const int bid = blockIdx.x;
    const int b0 = ((bid >> 3) & 7) * 128;                 // batch tile (8)
    const int n0 = ((bid & 7) + ((bid >> 6) << 3)) * 128;  // memory tile (512), XCD-grouped
    const int lane = tid & 63, wave = tid >> 6;
    const int wm = (wave >> 1) * 64, wn = (wave & 1) * 64;
    const int l15 = lane & 15, l4 = lane >> 4;

    f32x4 acc[4][4] = {};

    const int srow = tid >> 2;          // 0..63
    const int seg  = (tid & 3) * 8;
    const unsigned short* gA = qb + (size_t)(b0 + srow) * KDIM + seg;
    const unsigned short* gB = kb + (size_t)(n0 + srow) * KDIM + seg;
    const int lofs = srow * 32 + seg;   // byte offset tid*16: linear per wave

// issue one K-stage (4 GLD16, consistent order for vmcnt accounting)
#define STAGE(st) do {                                             \
    const int _ko = (st) * 32;                                     \
    GLD16(gA + _ko,             &As[(st) & 3][lofs]);              \
    GLD16(gA + _ko + 64 * KDIM, &As[(st) & 3][lofs + 64 * 32]);    \
    GLD16(gB + _ko,             &Bs[(st) & 3][lofs]);              \
    GLD16(gB + _ko + 64 * KDIM, &Bs[(st) & 3][lofs + 64 * 32]);    \
} while (0)

// one pipeline step: wait stage s landed (counted), barrier, prefetch s+3,
// ds_read + MFMA on buffer s&3. WN is a literal for the vmcnt immediate.
#define STEP(s, WN) do {                                                     \
    asm volatile("s_waitcnt vmcnt(" #WN ")" ::: "memory");                   \
    __builtin_amdgcn_s_barrier();                                            \
    asm volatile("" ::: "memory");                                           \
    if ((s) + 3 < 8) STAGE((s) + 3);                                         \
    bf16x8 qf[4], kf[4];                                                     \
    _Pragma("unroll")                                                        \
    for (int j = 0; j < 4; ++j)                                              \
        qf[j] = *(const bf16x8*)(&As[(s) & 3][(wm + j * 16 + l15) * 32 + l4 * 8]); \
    _Pragma("unroll")                                                        \
    for (int i = 0; i < 4; ++i)                                              \
        kf[i] = *(const bf16x8*)(&Bs[(s) & 3][(wn + i * 16 + l15) * 32 + l4 * 8]); \
    _Pragma("unroll")                                                        \
    for (int i = 0; i < 4; ++i)                                              \
        _Pragma("unroll")                                                    \
        for (int j = 0; j < 4; ++j)                                          \
            acc[i][j] = __builtin_amdgcn_mfma_f32_16x16x32_bf16(kf[i], qf[j], acc[i][j], 0, 0, 0); \
} while (0)

    // prologue: stages 0,1,2 in flight (12 loads)
    STAGE(0); STAGE(1); STAGE(2);

    STEP(0, 8); STEP(1, 8); STEP(2, 8); STEP(3, 8);
    STEP(4, 8); STEP(5, 8); STEP(6, 4); STEP(7, 0);

#undef STEP
#undef STAGE

    // epilogue (swapped layout): within acc[i][j]:
    //   mem   = n0 + wn + i*16 + l4*4 + reg   (4 consecutive per lane)
    //   batch = b0 + wm + j*16 + l15
    float4 hj[4];
#pragma unroll
    for (int i = 0; i < 4; ++i) {
        float4 h = *(const float4*)&hist[n0 + wn + i * 16 + l4 * 4];
        hj[i] = make_float4((h.x + BETA) * KSCALE, (h.y + BETA) * KSCALE,
                            (h.z + BETA) * KSCALE, (h.w + BETA) * KSCALE);
    }
#pragma unroll
    for (int j = 0; j < 4; ++j) {
        const size_t row = (size_t)(b0 + wm + j * 16 + l15) * MSIZE;
#pragma unroll
        for (int i = 0; i < 4; ++i) {
            const float* hv = (const float*)&hj[i];
            unsigned int pk = 0;
#pragma unroll
            for (int reg = 0; reg < 4; ++reg) {
                float sc = __expf(acc[i][j][reg] - 1.0f) * hv[reg];
                pk |= (unsigned int)(unsigned char)(int)fminf(sc, 255.0f) << (8 * reg);
            }
            *(unsigned int*)(s8 + row + (n0 + wn + i * 16 + l4 * 4)) = pk;
        }
    }
}

// -------------------------------------------------------------------------
// Kernel 2: per batch row, latency-optimized (unchanged from round 3):
//   pass 1: histogram of bytes >= 128 only (word prescreen), exact fallback;
//   single-wave shfl suffix-scan; pass 2 prescreened collect; 16-lane-group
//   rescore; exact count-based top-128; weighted sum.
// -------------------------------------------------------------------------
__global__ __launch_bounds__(256, 4)
void select_kernel(const float* __restrict__ q,
                   const float* __restrict__ key,
                   const float* __restrict__ hist,
                   const float* __restrict__ vals,
                   const unsigned char* __restrict__ s8,
                   float* __restrict__ out)
{
    const int b   = blockIdx.x;
    const int tid = threadIdx.x;

    __shared__ __align__(16) float qs[KDIM];
    __shared__ unsigned int hcnt[16 * 257];   // 16 replicated histograms
    __shared__ int   stot[256];
    __shared__ int   scal[2];                 // 0:H  1:ncand
    __shared__ int   cidx[1024];
    __shared__ float csc[1024], cjj[1024], cjv[1024];
    __shared__ float wred[8];

    qs[tid] = q[(size_t)b * KDIM + tid];
    const uint4* rowp = reinterpret_cast<const uint4*>(s8 + (size_t)b * MSIZE);
    const int rep = (tid & 15) * 257;

    // ---- threshold search: prescreened histogram, exact fallback ----
    int H = -1;
    int minb = 128;
    for (;;) {
        for (int i = tid; i < 16 * 257; i += 256) hcnt[i] = 0u;
        if (tid == 0) { scal[0] = -1; scal[1] = 0; }
        __syncthreads();

        for (int i = 0; i < 16; ++i) {
            uint4 v = rowp[i * 256 + tid];
            unsigned int w[4] = {v.x, v.y, v.z, v.w};
#pragma unroll
            for (int k = 0; k < 4; ++k) {
                if (minb == 0 || (w[k] & 0x80808080u)) {
#pragma unroll
                    for (int jj = 0; jj < 4; ++jj) {
                        int bb = (int)((w[k] >> (8 * jj)) & 0xffu);
                        if (bb >= minb) atomicAdd(&hcnt[rep + bb], 1u);
                    }
                }
            }
        }
        __syncthreads();
        { unsigned int t = 0;
#pragma unroll
          for (int k = 0; k < 16; ++k) t += hcnt[k * 257 + tid];
          stot[tid] = (int)t; }
        __syncthreads();

        // single-wave suffix scan over 256 bins; find crossing S[b]>=SELK>S[b+1]
        if (tid < 64) {
            const int l = tid;
            int t0 = stot[l * 4], t1 = stot[l * 4 + 1], t2 = stot[l * 4 + 2], t3 = stot[l * 4 + 3];
            int lsum = t0 + t1 + t2 + t3;
            int s = lsum;
#pragma unroll
            for (int off = 1; off < 64; off <<= 1) {
                int u = __shfl_down(s, off, 64);
                if (l + off < 64) s += u;
            }
            int A  = s - lsum;        // sum over lanes > l (== S[4l+4])
            int S3 = A + t3;
            int S2 = S3 + t2;
            int S1 = S2 + t1;
            int S0 = S1 + t0;
            if (S0 >= SELK && S1 < SELK) scal[0] = l * 4 + 0;
            if (S1 >= SELK && S2 < SELK) scal[0] = l * 4 + 1;
            if (S2 >= SELK && S3 < SELK) scal[0] = l * 4 + 2;
            if (S3 >= SELK && A  < SELK) scal[0] = l * 4 + 3;
        }
        __syncthreads();
        H = scal[0];
        __syncthreads();              // all threads read H before next-iter rewrites
        if (H >= 0) break;
        minb = 0;                     // threshold below 128: exact full histogram
    }

    // ---- pass 2: collect candidates (byte >= H); row re-read hits L3 ----
    const unsigned int uH = (unsigned int)H;
    const bool pre = (H >= 128);
    for (int i = 0; i < 16; ++i) {
        uint4 v = rowp[i * 256 + tid];
        const int base = (i * 256 + tid) * 16;
        unsigned int w[4] = {v.x, v.y, v.z, v.w};
#pragma unroll
        for (int k = 0; k < 4; ++k) {
            if (!pre || (w[k] & 0x80808080u)) {
#pragma unroll
                for (int jj = 0; jj < 4; ++jj) {
                    unsigned int bb = (w[k] >> (8 * jj)) & 0xffu;
                    if (bb >= uH) {
                        int p = atomicAdd(&scal[1], 1);
                        if (p < 1024) cidx[p] = base + 4 * k + jj;
                    }
                }
            }
        }
    }
    __syncthreads();
    const int ncand = min(scal[1], 1024);

    // ---- exact fp32 rescore: 16-lane groups, 4 candidates per wave in flight ----
    const int gid = tid >> 4, gl = tid & 15;
    const float4* q4 = (const float4*)qs;
    for (int i = gid; i < ncand; i += 16) {
        const int idx = cidx[i];
        const float4* kp = (const float4*)(key + (size_t)idx * KDIM);
        float p = 0.f;
#pragma unroll
        for (int u = 0; u < 4; ++u) {
            float4 kk = kp[gl * 4 + u];
            float4 qq = q4[gl * 4 + u];
            p += kk.x * qq.x + kk.y * qq.y + kk.z * qq.z + kk.w * qq.w;
        }
#pragma unroll
        for (int off = 1; off < 16; off <<= 1) p += __shfl_xor(p, off, 64);
        if (gl == 0) {
            float e = expf(p - 1.0f);
            float h = hist[idx];
            csc[i] = e * (h + BETA);
            float j = e * (ALPHA * h + BETA);
            cjj[i] = j;
            cjv[i] = j * vals[idx];
        }
    }
    __syncthreads();

    // ---- exact top-128 among candidates (count-based; ties -> lower index) ----
    const int wave = tid >> 6, lane = tid & 63;
    float pn = 0.f, pd = 0.f;
    for (int i = tid; i < ncand; i += 256) {
        float si = csc[i]; int ii = cidx[i]; int rank = 0;
        for (int t = 0; t < ncand; ++t) {
            float st = csc[t];
            rank += (st > si || (st == si && cidx[t] < ii)) ? 1 : 0;
        }
        if (rank < CHOOSEK) { pn += cjv[i]; pd += cjj[i]; }
    }
#pragma unroll
    for (int off = 32; off > 0; off >>= 1) {
        pn += __shfl_xor(pn, off, 64);
        pd += __shfl_xor(pd, off, 64);
    }
    if (lane == 0) { wred[wave] = pn; wred[4 + wave] = pd; }
    __syncthreads();
    if (tid == 0) {
        float n = wred[0] + wred[1] + wred[2] + wred[3];
        float d = wred[4] + wred[5] + wred[6] + wred[7];
        out[b] = n / d;
    }
}

// -------------------------------------------------------------------------
extern "C" void kernel_launch(void* const* d_in, const int* in_sizes, int n_in,
                              void* d_out, int out_size, void* d_ws, size_t ws_size,
                              hipStream_t stream)
{
    (void)in_sizes; (void)n_in; (void)out_size; (void)ws_size;
    const float* q    = (const float*)d_in[0];
    const float* key  = (const float*)d_in[1];
    const float* hist = (const float*)d_in[2];
    const float* vals = (const float*)d_in[3];
    float* out = (float*)d_out;

    // workspace layout (96.5 MiB total):
    unsigned char*  s8 = (unsigned char*)d_ws;                                  // 64 MiB u8 keys
    unsigned short* kb = (unsigned short*)((char*)d_ws + ((size_t)64 << 20));   // 32 MiB bf16 key
    unsigned short* qb = (unsigned short*)((char*)d_ws + ((size_t)96 << 20));   // 512 KiB bf16 q

    convert_kernel<<<8320, 256, 0, stream>>>(q, key, qb, kb);
    score_kernel<<<4096, 256, 0, stream>>>(qb, kb, hist, s8);
    select_kernel<<<BATCH, 256, 0, stream>>>(q, key, hist, vals, s8, out);
}

// Round 6
// 223.132 us; speedup vs baseline: 1.1176x; 1.0041x over previous
//
#include <hip/hip_runtime.h>

#define BATCH   1024
#define MSIZE   65536
#define KDIM    256
#define CHOOSEK 128
#define SELK    160        // suffix-count crossing target; superset = SELK..SELK+bucket
#define BETA    1e-8f
#define ALPHA   0.5f
// linear u8 key: key = min(255, score*KSCALE). score <= exp(sim-1)*(histmax+beta);
// sims ~ N(0,1/16) => score <~ 6e-4 whp. KSCALE = 256/6e-4. Threshold byte ~175-185,
// tail density ~25/bucket => ncand ~ [160, ~400] << 1024 cap. Monotone quantization
// keeps the screened superset exact.
#define KSCALE  426666.7f

typedef short bf16x8 __attribute__((ext_vector_type(8)));
typedef float f32x4  __attribute__((ext_vector_type(4)));

__device__ inline unsigned int pack2bf(float a, float b) {   // RNE fp32->bf16 pair
    unsigned int ua = __float_as_uint(a);
    unsigned int ub = __float_as_uint(b);
    ua += 0x7fffu + ((ua >> 16) & 1u);
    ub += 0x7fffu + ((ub >> 16) & 1u);
    return (ua >> 16) | (ub & 0xffff0000u);
}

// async global->LDS, 16B/lane; LDS dest is wave-uniform base + lane*16 (must be linear in tid)
#define GLD16(g, l) __builtin_amdgcn_global_load_lds( \
    (const __attribute__((address_space(1))) unsigned int*)(g), \
    (__attribute__((address_space(3))) unsigned int*)(l), 16, 0, 0)

// -------------------------------------------------------------------------
// Kernel 0: one-time fp32 -> bf16 convert of q and key.
// -------------------------------------------------------------------------
__global__ __launch_bounds__(256)
void convert_kernel(const float* __restrict__ q, const float* __restrict__ key,
                    unsigned short* __restrict__ qb, unsigned short* __restrict__ kb)
{
    const int id = blockIdx.x * 256 + threadIdx.x;
    const float* src; unsigned short* dst; int off;
    if (blockIdx.x < 128) { src = q;   dst = qb; off = id; }
    else                  { src = key; dst = kb; off = id - 32768; }
    const float4* s4 = (const float4*)src;
    float4 a = s4[off * 2];
    float4 b = s4[off * 2 + 1];
    uint4 p = make_uint4(pack2bf(a.x, a.y), pack2bf(a.z, a.w),
                         pack2bf(b.x, b.y), pack2bf(b.z, b.w));
    ((uint4*)dst)[off] = p;
}

// -------------------------------------------------------------------------
// Kernel 1: bf16 screening GEMM, 128x128 tile, BK=32, K=256 -> 8 stages.
// 3-buffer LDS ring (48 KB -> 3 blocks/CU): counted vmcnt(4) (never 0
// mid-loop), ONE raw s_barrier per step, prefetch distance 2.
//   r3 (2-buf drain-0, 4 blk/CU) = 73us; r5 (4-buf counted, 2 blk/CU) = 76us;
//   this is the untested counted+resident quadrant.
// Ring safety: buffer (s+2)%3 written at step s was last read at step s-1;
// every wave past barrier s has issued its step-(s-1) MFMAs, which required
// its ds_reads complete (compiler lgkm-waits before MFMA use).
// MFMA swapped: acc[i][j] = mfma(kf[i], qf[j]) -> lane's 4 regs = 4 consecutive
// mem slots of one batch row -> epilogue packs 4 u8 into one dword store.
// -------------------------------------------------------------------------
__global__ __launch_bounds__(256)
void score_kernel(const unsigned short* __restrict__ qb,
                  const unsigned short* __restrict__ kb,
                  const float* __restrict__ hist,
                  unsigned char* __restrict__ s8)
{
    __shared__ __align__(16) unsigned short As[3][128 * 32];   // 3 x 8 KB
    __shared__ __align__(16) unsigned short Bs[3][128 * 32];   // 3 x 8 KB
    const int tid = threadIdx.x;
    const int bid = blockIdx.x;
    const int b0 = ((bid >> 3) & 7) * 128;                 // batch tile (8)
    const int n0 = ((bid & 7) + ((bid >> 6) << 3)) * 128;  // memory tile (512), XCD-grouped
    const int lane = tid & 63, wave = tid >> 6;
    const int wm = (wave >> 1) * 64, wn = (wave & 1) * 64;
    const int l15 = lane & 15, l4 = lane >> 4;

    f32x4 acc[4][4] = {};

    const int srow = tid >> 2;          // 0..63
    const int seg  = (tid & 3) * 8;
    const unsigned short* gA = qb + (size_t)(b0 + srow) * KDIM + seg;
    const unsigned short* gB = kb + (size_t)(n0 + srow) * KDIM + seg;
    const int lofs = srow * 32 + seg;   // byte offset tid*16: linear per wave

// issue one K-stage (4 GLD16, consistent order for vmcnt accounting)
#define STAGE(st) do {                                               \
    const int _ko = (st) * 32;                                       \
    GLD16(gA + _ko,             &As[(st) % 3][lofs]);                \
    GLD16(gA + _ko + 64 * KDIM, &As[(st) % 3][lofs + 64 * 32]);     \
    GLD16(gB + _ko,             &Bs[(st) % 3][lofs]);                \
    GLD16(gB + _ko + 64 * KDIM, &Bs[(st) % 3][lofs + 64 * 32]);     \
} while (0)

// one pipeline step: counted wait (stage s landed; stage s+1 stays in flight),
// barrier, prefetch stage s+2 into the buffer read at step s-1, compute.
#define STEP(s, WN) do {                                                     \
    asm volatile("s_waitcnt vmcnt(" #WN ")" ::: "memory");                   \
    __builtin_amdgcn_s_barrier();                                            \
    asm volatile("" ::: "memory");                                           \
    if ((s) + 2 < 8) STAGE((s) + 2);                                         \
    bf16x8 qf[4], kf[4];                                                     \
    _Pragma("unroll")                                                        \
    for (int j = 0; j < 4; ++j)                                              \
        qf[j] = *(const bf16x8*)(&As[(s) % 3][(wm + j * 16 + l15) * 32 + l4 * 8]); \
    _Pragma("unroll")                                                        \
    for (int i = 0; i < 4; ++i)                                              \
        kf[i] = *(const bf16x8*)(&Bs[(s) % 3][(wn + i * 16 + l15) * 32 + l4 * 8]); \
    _Pragma("unroll")                                                        \
    for (int i = 0; i < 4; ++i)                                              \
        _Pragma("unroll")                                                    \
        for (int j = 0; j < 4; ++j)                                          \
            acc[i][j] = __builtin_amdgcn_mfma_f32_16x16x32_bf16(kf[i], qf[j], acc[i][j], 0, 0, 0); \
} while (0)

    // prologue: stages 0,1 in flight (8 loads)
    STAGE(0); STAGE(1);

    STEP(0, 4); STEP(1, 4); STEP(2, 4); STEP(3, 4);
    STEP(4, 4); STEP(5, 4); STEP(6, 4); STEP(7, 0);

#undef STEP
#undef STAGE

    // epilogue (swapped layout): within acc[i][j]:
    //   mem   = n0 + wn + i*16 + l4*4 + reg   (4 consecutive per lane)
    //   batch = b0 + wm + j*16 + l15
    float4 hj[4];
#pragma unroll
    for (int i = 0; i < 4; ++i) {
        float4 h = *(const float4*)&hist[n0 + wn + i * 16 + l4 * 4];
        hj[i] = make_float4((h.x + BETA) * KSCALE, (h.y + BETA) * KSCALE,
                            (h.z + BETA) * KSCALE, (h.w + BETA) * KSCALE);
    }
#pragma unroll
    for (int j = 0; j < 4; ++j) {
        const size_t row = (size_t)(b0 + wm + j * 16 + l15) * MSIZE;
#pragma unroll
        for (int i = 0; i < 4; ++i) {
            const float* hv = (const float*)&hj[i];
            unsigned int pk = 0;
#pragma unroll
            for (int reg = 0; reg < 4; ++reg) {
                float sc = __expf(acc[i][j][reg] - 1.0f) * hv[reg];
                pk |= (unsigned int)(unsigned char)(int)fminf(sc, 255.0f) << (8 * reg);
            }
            *(unsigned int*)(s8 + row + (n0 + wn + i * 16 + l4 * 4)) = pk;
        }
    }
}

// -------------------------------------------------------------------------
// Kernel 2: per batch row.
//   pass 1: histogram only bytes >= 160 (exact word test
//           w & ((w<<1)|(w<<2)) & 0x80808080 <=> any byte >= 160; threshold
//           byte lands ~175-185 so ~4x fewer atomics than bit7 prescreen).
//           Exact full-histogram fallback if no crossing found.
//   single-wave shfl suffix-scan; pass 2 word-masked collect; 16-lane-group
//   rescore; exact count-based top-128 (ties -> lower index); weighted sum.
// -------------------------------------------------------------------------
__global__ __launch_bounds__(256, 4)
void select_kernel(const float* __restrict__ q,
                   const float* __restrict__ key,
                   const float* __restrict__ hist,
                   const float* __restrict__ vals,
                   const unsigned char* __restrict__ s8,
                   float* __restrict__ out)
{
    const int b   = blockIdx.x;
    const int tid = threadIdx.x;

    __shared__ __align__(16) float qs[KDIM];
    __shared__ unsigned int hcnt[16 * 257];   // 16 replicated histograms
    __shared__ int   stot[256];
    __shared__ int   scal[2];                 // 0:H  1:ncand
    __shared__ int   cidx[1024];
    __shared__ float csc[1024], cjj[1024], cjv[1024];
    __shared__ float wred[8];

    qs[tid] = q[(size_t)b * KDIM + tid];
    const uint4* rowp = reinterpret_cast<const uint4*>(s8 + (size_t)b * MSIZE);
    const int rep = (tid & 15) * 257;

    // ---- threshold search: >=160-prescreened histogram, exact fallback ----
    int H = -1;
    int minb = 160;
    for (;;) {
        for (int i = tid; i < 16 * 257; i += 256) hcnt[i] = 0u;
        if (tid == 0) { scal[0] = -1; scal[1] = 0; }
        __syncthreads();

        for (int i = 0; i < 16; ++i) {
            uint4 v = rowp[i * 256 + tid];
            unsigned int w[4] = {v.x, v.y, v.z, v.w};
#pragma unroll
            for (int k = 0; k < 4; ++k) {
                unsigned int msk = minb ? (w[k] & ((w[k] << 1) | (w[k] << 2)) & 0x80808080u) : 1u;
                if (msk) {
#pragma unroll
                    for (int jj = 0; jj < 4; ++jj) {
                        int bb = (int)((w[k] >> (8 * jj)) & 0xffu);
                        if (bb >= minb) atomicAdd(&hcnt[rep + bb], 1u);
                    }
                }
            }
        }
        __syncthreads();
        { unsigned int t = 0;
#pragma unroll
          for (int k = 0; k < 16; ++k) t += hcnt[k * 257 + tid];
          stot[tid] = (int)t; }
        __syncthreads();

        // single-wave suffix scan over 256 bins; find crossing S[b]>=SELK>S[b+1]
        if (tid < 64) {
            const int l = tid;
            int t0 = stot[l * 4], t1 = stot[l * 4 + 1], t2 = stot[l * 4 + 2], t3 = stot[l * 4 + 3];
            int lsum = t0 + t1 + t2 + t3;
            int s = lsum;
#pragma unroll
            for (int off = 1; off < 64; off <<= 1) {
                int u = __shfl_down(s, off, 64);
                if (l + off < 64) s += u;
            }
            int A  = s - lsum;        // sum over lanes > l (== S[4l+4])
            int S3 = A + t3;
            int S2 = S3 + t2;
            int S1 = S2 + t1;
            int S0 = S1 + t0;
            if (S0 >= SELK && S1 < SELK) scal[0] = l * 4 + 0;
            if (S1 >= SELK && S2 < SELK) scal[0] = l * 4 + 1;
            if (S2 >= SELK && S3 < SELK) scal[0] = l * 4 + 2;
            if (S3 >= SELK && A  < SELK) scal[0] = l * 4 + 3;
        }
        __syncthreads();
        H = scal[0];
        __syncthreads();              // all threads read H before next-iter rewrites
        if (H >= 0) break;
        minb = 0;                     // threshold below prescreen: exact full histogram
    }

    // ---- pass 2: collect candidates (byte >= H); row re-read hits L3 ----
    const unsigned int uH = (unsigned int)H;
    const int mmode = (H >= 160) ? 2 : (H >= 128) ? 1 : 0;
    for (int i = 0; i < 16; ++i) {
        uint4 v = rowp[i * 256 + tid];
        const int base = (i * 256 + tid) * 16;
        unsigned int w[4] = {v.x, v.y, v.z, v.w};
#pragma unroll
        for (int k = 0; k < 4; ++k) {
            unsigned int msk = (mmode == 2) ? (w[k] & ((w[k] << 1) | (w[k] << 2)) & 0x80808080u)
                             : (mmode == 1) ? (w[k] & 0x80808080u) : 1u;
            if (msk) {
#pragma unroll
                for (int jj = 0; jj < 4; ++jj) {
                    unsigned int bb = (w[k] >> (8 * jj)) & 0xffu;
                    if (bb >= uH) {
                        int p = atomicAdd(&scal[1], 1);
                        if (p < 1024) cidx[p] = base + 4 * k + jj;
                    }
                }
            }
        }
    }
    __syncthreads();
    const int ncand = min(scal[1], 1024);

    // ---- exact fp32 rescore: 16-lane groups, 4 candidates per wave in flight ----
    const int gid = tid >> 4, gl = tid & 15;
    const float4* q4 = (const float4*)qs;
    for (int i = gid; i < ncand; i += 16) {
        const int idx = cidx[i];
        const float4* kp = (const float4*)(key + (size_t)idx * KDIM);
        float p = 0.f;
#pragma unroll
        for (int u = 0; u < 4; ++u) {
            float4 kk = kp[gl * 4 + u];
            float4 qq = q4[gl * 4 + u];
            p += kk.x * qq.x + kk.y * qq.y + kk.z * qq.z + kk.w * qq.w;
        }
#pragma unroll
        for (int off = 1; off < 16; off <<= 1) p += __shfl_xor(p, off, 64);
        if (gl == 0) {
            float e = expf(p - 1.0f);
            float h = hist[idx];
            csc[i] = e * (h + BETA);
            float j = e * (ALPHA * h + BETA);
            cjj[i] = j;
            cjv[i] = j * vals[idx];
        }
    }
    __syncthreads();

    // ---- exact top-128 among candidates (count-based; ties -> lower index) ----
    const int wave = tid >> 6, lane = tid & 63;
    float pn = 0.f, pd = 0.f;
    for (int i = tid; i < ncand; i += 256) {
        float si = csc[i]; int ii = cidx[i]; int rank = 0;
        for (int t = 0; t < ncand; ++t) {
            float st = csc[t];
            rank += (st > si || (st == si && cidx[t] < ii)) ? 1 : 0;
        }
        if (rank < CHOOSEK) { pn += cjv[i]; pd += cjj[i]; }
    }
#pragma unroll
    for (int off = 32; off > 0; off >>= 1) {
        pn += __shfl_xor(pn, off, 64);
        pd += __shfl_xor(pd, off, 64);
    }
    if (lane == 0) { wred[wave] = pn; wred[4 + wave] = pd; }
    __syncthreads();
    if (tid == 0) {
        float n = wred[0] + wred[1] + wred[2] + wred[3];
        float d = wred[4] + wred[5] + wred[6] + wred[7];
        out[b] = n / d;
    }
}

// -------------------------------------------------------------------------
extern "C" void kernel_launch(void* const* d_in, const int* in_sizes, int n_in,
                              void* d_out, int out_size, void* d_ws, size_t ws_size,
                              hipStream_t stream)
{
    (void)in_sizes; (void)n_in; (void)out_size; (void)ws_size;
    const float* q    = (const float*)d_in[0];
    const float* key  = (const float*)d_in[1];
    const float* hist = (const float*)d_in[2];
    const float* vals = (const float*)d_in[3];
    float* out = (float*)d_out;

    // workspace layout (96.5 MiB total):
    unsigned char*  s8 = (unsigned char*)d_ws;                                  // 64 MiB u8 keys
    unsigned short* kb = (unsigned short*)((char*)d_ws + ((size_t)64 << 20));   // 32 MiB bf16 key
    unsigned short* qb = (unsigned short*)((char*)d_ws + ((size_t)96 << 20));   // 512 KiB bf16 q

    convert_kernel<<<8320, 256, 0, stream>>>(q, key, qb, kb);
    score_kernel<<<4096, 256, 0, stream>>>(qb, kb, hist, s8);
    select_kernel<<<BATCH, 256, 0, stream>>>(q, key, hist, vals, s8, out);
}

// Round 7
// 212.827 us; speedup vs baseline: 1.1717x; 1.0484x over previous
//
#include <hip/hip_runtime.h>

#define BATCH   1024
#define MSIZE   65536
#define KDIM    256
#define CHOOSEK 128
#define SELK    160        // suffix-count crossing target
#define BETA    1e-8f
#define ALPHA   0.5f
// u8 key = clamp((sim + log(hist+beta) + KOFF) * KSC). Monotone in score (log map, no exp).
// Threshold byte ~165-175; bucket = 1/425 log-units vs bf16 screening error ~2.5e-4 -> ~10 sigma
// per bucket, SELK-CHOOSEK=32 ranks ~ 3 buckets margin. bytes>=128 ~ 1.8K/row (bit7 prescreen ok).
#define KSC  425.0f
#define KOFF 7.2f

typedef short bf16x8 __attribute__((ext_vector_type(8)));
typedef float f32x4  __attribute__((ext_vector_type(4)));

__device__ inline unsigned int pack2bf(float a, float b) {   // RNE fp32->bf16 pair
    unsigned int ua = __float_as_uint(a);
    unsigned int ub = __float_as_uint(b);
    ua += 0x7fffu + ((ua >> 16) & 1u);
    ub += 0x7fffu + ((ub >> 16) & 1u);
    return (ua >> 16) | (ub & 0xffff0000u);
}

// async global->LDS, 16B/lane; LDS dest is wave-uniform base + lane*16 (must be linear in tid)
#define GLD16(g, l) __builtin_amdgcn_global_load_lds( \
    (const __attribute__((address_space(1))) unsigned int*)(g), \
    (__attribute__((address_space(3))) unsigned int*)(l), 16, 0, 0)

// -------------------------------------------------------------------------
// Kernel 0: one-time preprocessing.
//  blocks [0,8192):      key fp32 -> bf16 (kb)
//  blocks [8192,8320):   q fp32 -> bf16 in FRAGMENT order (qs):
//      frag f = (((bt*2+wmg)*8+ks)*4+j)*64 + lane holds q row
//      bt*128+wmg*64+j*16+(lane&15), cols ks*32+(lane>>4)*8 .. +8  (16 B)
//      -> score kernel reads each fragment as ONE coalesced dwordx4/wave.
//  blocks [8320,8576):   L[n] = (log(hist[n]+BETA)+KOFF)*KSC  (epilogue table)
// -------------------------------------------------------------------------
__global__ __launch_bounds__(256)
void convert_kernel(const float* __restrict__ q, const float* __restrict__ key,
                    const float* __restrict__ hist,
                    unsigned short* __restrict__ qs, unsigned short* __restrict__ kb,
                    float* __restrict__ Ltab)
{
    const int bid = blockIdx.x, tid = threadIdx.x;
    if (bid < 8192) {                       // key convert
        const int off = bid * 256 + tid;
        const float4* s4 = (const float4*)key;
        float4 a = s4[off * 2], b = s4[off * 2 + 1];
        ((uint4*)kb)[off] = make_uint4(pack2bf(a.x, a.y), pack2bf(a.z, a.w),
                                       pack2bf(b.x, b.y), pack2bf(b.z, b.w));
    } else if (bid < 8320) {                // q fragment-swizzle
        const int f = (bid - 8192) * 256 + tid;
        const int l = f & 63, j = (f >> 6) & 3, ks = (f >> 8) & 7;
        const int wmg = (f >> 11) & 1, bt = f >> 12;
        const int r = bt * 128 + wmg * 64 + j * 16 + (l & 15);
        const int c = ks * 32 + (l >> 4) * 8;
        const float* src = q + (size_t)r * KDIM + c;
        float4 a = *(const float4*)src, b = *(const float4*)(src + 4);
        ((uint4*)qs)[f] = make_uint4(pack2bf(a.x, a.y), pack2bf(a.z, a.w),
                                     pack2bf(b.x, b.y), pack2bf(b.z, b.w));
    } else {                                // L table
        const int n = (bid - 8320) * 256 + tid;
        Ltab[n] = (logf(hist[n] + BETA) + KOFF) * KSC;
    }
}

// -------------------------------------------------------------------------
// Kernel 1: bf16 screening GEMM, 128x128 tile, BK=32, K=256 -> 8 steps.
//  - B (key) staged in 3-buffer LDS ring (24 KB), counted vmcnt(2), one raw
//    s_barrier per step (manual wait covers ONLY the B ring; the q register
//    loads are compiler-tracked).
//  - A (q) fragments: one coalesced global_load_dwordx4 per (step,j) per wave
//    from the 512 KB L2-resident fragment table (r4's failure was SCATTERED
//    per-lane loads; these are 1 KB/instr contiguous).
//  - Epilogue: byte = clamp(fma(sim, KSC, L[n])) -- no exp, 3 VALU/value.
// MFMA swapped: acc[i][j] = mfma(kf[i], qf[j]) -> lane's 4 acc regs = 4
// consecutive mem slots of one batch row -> packed dword stores.
// -------------------------------------------------------------------------
__global__ __launch_bounds__(256, 3)
void score_kernel(const unsigned short* __restrict__ qs,
                  const unsigned short* __restrict__ kb,
                  const float* __restrict__ Ltab,
                  unsigned char* __restrict__ s8)
{
    __shared__ __align__(16) unsigned short Bs[3][128 * 32];   // 3 x 8 KB
    const int tid = threadIdx.x;
    const int bid = blockIdx.x;
    const int b0 = ((bid >> 3) & 7) * 128;                 // batch tile (8)
    const int n0 = ((bid & 7) + ((bid >> 6) << 3)) * 128;  // memory tile (512), XCD-grouped
    const int lane = tid & 63, wave = tid >> 6;
    const int wm = (wave >> 1) * 64, wn = (wave & 1) * 64;
    const int l15 = lane & 15, l4 = lane >> 4;
    const int bt = (bid >> 3) & 7, wmg = wave >> 1;

    f32x4 acc[4][4] = {};

    const int srow = tid >> 2;          // 0..63
    const int seg  = (tid & 3) * 8;
    const unsigned short* gB = kb + (size_t)(n0 + srow) * KDIM + seg;
    const int lofs = srow * 32 + seg;   // byte offset tid*16: linear per wave

    // per-wave fragment base: qw[(s*4+j)*64] is this lane's 16B A-fragment
    const bf16x8* qw = (const bf16x8*)qs + ((bt * 2 + wmg) * 8) * 4 * 64 + lane;

#define STAGE_B(st) do {                                             \
    const int _ko = (st) * 32;                                       \
    GLD16(gB + _ko,             &Bs[(st) % 3][lofs]);                \
    GLD16(gB + _ko + 64 * KDIM, &Bs[(st) % 3][lofs + 64 * 32]);     \
} while (0)

// step: counted wait for B ring (q loads handled by compiler), barrier,
// q-frag loads (coalesced), prefetch B(s+2), ds_read B frags, 16 MFMA.
#define STEP(s, WN) do {                                                     \
    asm volatile("s_waitcnt vmcnt(" #WN ")" ::: "memory");                   \
    __builtin_amdgcn_s_barrier();                                            \
    asm volatile("" ::: "memory");                                           \
    bf16x8 qf[4];                                                            \
    _Pragma("unroll")                                                        \
    for (int j = 0; j < 4; ++j) qf[j] = qw[(((s) * 4 + j) * 64)];            \
    if ((s) + 2 < 8) STAGE_B((s) + 2);                                       \
    bf16x8 kf[4];                                                            \
    _Pragma("unroll")                                                        \
    for (int i = 0; i < 4; ++i)                                              \
        kf[i] = *(const bf16x8*)(&Bs[(s) % 3][(wn + i * 16 + l15) * 32 + l4 * 8]); \
    _Pragma("unroll")                                                        \
    for (int i = 0; i < 4; ++i)                                              \
        _Pragma("unroll")                                                    \
        for (int j = 0; j < 4; ++j)                                          \
            acc[i][j] = __builtin_amdgcn_mfma_f32_16x16x32_bf16(kf[i], qf[j], acc[i][j], 0, 0, 0); \
} while (0)

    // prologue: B stages 0,1 in flight (4 loads)
    STAGE_B(0); STAGE_B(1);

    STEP(0, 2); STEP(1, 2); STEP(2, 2); STEP(3, 2);
    STEP(4, 2); STEP(5, 2); STEP(6, 2); STEP(7, 0);

#undef STEP
#undef STAGE_B

    // epilogue: within acc[i][j]: mem = n0+wn+i*16+l4*4+reg, batch = b0+wm+j*16+l15
    float4 Lv[4];
#pragma unroll
    for (int i = 0; i < 4; ++i)
        Lv[i] = *(const float4*)&Ltab[n0 + wn + i * 16 + l4 * 4];
#pragma unroll
    for (int j = 0; j < 4; ++j) {
        const size_t row = (size_t)(b0 + wm + j * 16 + l15) * MSIZE;
#pragma unroll
        for (int i = 0; i < 4; ++i) {
            const float* lv = (const float*)&Lv[i];
            unsigned int pk = 0;
#pragma unroll
            for (int reg = 0; reg < 4; ++reg) {
                float x = fmaf(acc[i][j][reg], KSC, lv[reg]);
                x = fminf(fmaxf(x, 0.0f), 255.0f);
                pk |= (unsigned int)(int)x << (8 * reg);
            }
            *(unsigned int*)(s8 + row + (n0 + wn + i * 16 + l4 * 4)) = pk;
        }
    }
}

// -------------------------------------------------------------------------
// Kernel 2: per batch row (r3-proven structure, prescreen back at 128):
//   pass 1: histogram only bytes >= 128 (bit7 word test), exact full-histogram
//           fallback if no crossing; single-wave shfl suffix-scan;
//   pass 2: word-masked collect (superset of exact top-128);
//   16-lane-group exact fp32 rescore; count-based exact top-128
//   (ties -> lower index); weighted sum.
// -------------------------------------------------------------------------
__global__ __launch_bounds__(256, 4)
void select_kernel(const float* __restrict__ q,
                   const float* __restrict__ key,
                   const float* __restrict__ hist,
                   const float* __restrict__ vals,
                   const unsigned char* __restrict__ s8,
                   float* __restrict__ out)
{
    const int b   = blockIdx.x;
    const int tid = threadIdx.x;

    __shared__ __align__(16) float qs[KDIM];
    __shared__ unsigned int hcnt[16 * 257];   // 16 replicated histograms
    __shared__ int   stot[256];
    __shared__ int   scal[2];                 // 0:H  1:ncand
    __shared__ int   cidx[1024];
    __shared__ float csc[1024], cjj[1024], cjv[1024];
    __shared__ float wred[8];

    qs[tid] = q[(size_t)b * KDIM + tid];
    const uint4* rowp = reinterpret_cast<const uint4*>(s8 + (size_t)b * MSIZE);
    const int rep = (tid & 15) * 257;

    // ---- threshold search: bit7-prescreened histogram, exact fallback ----
    int H = -1;
    int minb = 128;
    for (;;) {
        for (int i = tid; i < 16 * 257; i += 256) hcnt[i] = 0u;
        if (tid == 0) { scal[0] = -1; scal[1] = 0; }
        __syncthreads();

        for (int i = 0; i < 16; ++i) {
            uint4 v = rowp[i * 256 + tid];
            unsigned int w[4] = {v.x, v.y, v.z, v.w};
#pragma unroll
            for (int k = 0; k < 4; ++k) {
                if (minb == 0 || (w[k] & 0x80808080u)) {
#pragma unroll
                    for (int jj = 0; jj < 4; ++jj) {
                        int bb = (int)((w[k] >> (8 * jj)) & 0xffu);
                        if (bb >= minb) atomicAdd(&hcnt[rep + bb], 1u);
                    }
                }
            }
        }
        __syncthreads();
        { unsigned int t = 0;
#pragma unroll
          for (int k = 0; k < 16; ++k) t += hcnt[k * 257 + tid];
          stot[tid] = (int)t; }
        __syncthreads();

        // single-wave suffix scan over 256 bins; find crossing S[b]>=SELK>S[b+1]
        if (tid < 64) {
            const int l = tid;
            int t0 = stot[l * 4], t1 = stot[l * 4 + 1], t2 = stot[l * 4 + 2], t3 = stot[l * 4 + 3];
            int lsum = t0 + t1 + t2 + t3;
            int s = lsum;
#pragma unroll
            for (int off = 1; off < 64; off <<= 1) {
                int u = __shfl_down(s, off, 64);
                if (l + off < 64) s += u;
            }
            int A  = s - lsum;        // sum over lanes > l (== S[4l+4])
            int S3 = A + t3;
            int S2 = S3 + t2;
            int S1 = S2 + t1;
            int S0 = S1 + t0;
            if (S0 >= SELK && S1 < SELK) scal[0] = l * 4 + 0;
            if (S1 >= SELK && S2 < SELK) scal[0] = l * 4 + 1;
            if (S2 >= SELK && S3 < SELK) scal[0] = l * 4 + 2;
            if (S3 >= SELK && A  < SELK) scal[0] = l * 4 + 3;
        }
        __syncthreads();
        H = scal[0];
        __syncthreads();              // all threads read H before next-iter rewrites
        if (H >= 0) break;
        minb = 0;                     // threshold below 128: exact full histogram
    }

    // ---- pass 2: collect candidates (byte >= H); row re-read hits L3 ----
    const unsigned int uH = (unsigned int)H;
    const bool pre = (H >= 128);
    for (int i = 0; i < 16; ++i) {
        uint4 v = rowp[i * 256 + tid];
        const int base = (i * 256 + tid) * 16;
        unsigned int w[4] = {v.x, v.y, v.z, v.w};
#pragma unroll
        for (int k = 0; k < 4; ++k) {
            if (!pre || (w[k] & 0x80808080u)) {
#pragma unroll
                for (int jj = 0; jj < 4; ++jj) {
                    unsigned int bb = (w[k] >> (8 * jj)) & 0xffu;
                    if (bb >= uH) {
                        int p = atomicAdd(&scal[1], 1);
                        if (p < 1024) cidx[p] = base + 4 * k + jj;
                    }
                }
            }
        }
    }
    __syncthreads();
    const int ncand = min(scal[1], 1024);

    // ---- exact fp32 rescore: 16-lane groups, 4 candidates per wave in flight ----
    const int gid = tid >> 4, gl = tid & 15;
    const float4* q4 = (const float4*)qs;
    for (int i = gid; i < ncand; i += 16) {
        const int idx = cidx[i];
        const float4* kp = (const float4*)(key + (size_t)idx * KDIM);
        float p = 0.f;
#pragma unroll
        for (int u = 0; u < 4; ++u) {
            float4 kk = kp[gl * 4 + u];
            float4 qq = q4[gl * 4 + u];
            p += kk.x * qq.x + kk.y * qq.y + kk.z * qq.z + kk.w * qq.w;
        }
#pragma unroll
        for (int off = 1; off < 16; off <<= 1) p += __shfl_xor(p, off, 64);
        if (gl == 0) {
            float e = expf(p - 1.0f);
            float h = hist[idx];
            csc[i] = e * (h + BETA);
            float j = e * (ALPHA * h + BETA);
            cjj[i] = j;
            cjv[i] = j * vals[idx];
        }
    }
    __syncthreads();

    // ---- exact top-128 among candidates (count-based; ties -> lower index) ----
    const int wave = tid >> 6, lane = tid & 63;
    float pn = 0.f, pd = 0.f;
    for (int i = tid; i < ncand; i += 256) {
        float si = csc[i]; int ii = cidx[i]; int rank = 0;
        for (int t = 0; t < ncand; ++t) {
            float st = csc[t];
            rank += (st > si || (st == si && cidx[t] < ii)) ? 1 : 0;
        }
        if (rank < CHOOSEK) { pn += cjv[i]; pd += cjj[i]; }
    }
#pragma unroll
    for (int off = 32; off > 0; off >>= 1) {
        pn += __shfl_xor(pn, off, 64);
        pd += __shfl_xor(pd, off, 64);
    }
    if (lane == 0) { wred[wave] = pn; wred[4 + wave] = pd; }
    __syncthreads();
    if (tid == 0) {
        float n = wred[0] + wred[1] + wred[2] + wred[3];
        float d = wred[4] + wred[5] + wred[6] + wred[7];
        out[b] = n / d;
    }
}

// -------------------------------------------------------------------------
extern "C" void kernel_launch(void* const* d_in, const int* in_sizes, int n_in,
                              void* d_out, int out_size, void* d_ws, size_t ws_size,
                              hipStream_t stream)
{
    (void)in_sizes; (void)n_in; (void)out_size; (void)ws_size;
    const float* q    = (const float*)d_in[0];
    const float* key  = (const float*)d_in[1];
    const float* hist = (const float*)d_in[2];
    const float* vals = (const float*)d_in[3];
    float* out = (float*)d_out;

    // workspace layout (97.25 MiB total):
    unsigned char*  s8 = (unsigned char*)d_ws;                                   // 64 MiB u8 keys
    unsigned short* kb = (unsigned short*)((char*)d_ws + ((size_t)64 << 20));    // 32 MiB bf16 key
    unsigned short* qsw= (unsigned short*)((char*)d_ws + ((size_t)96 << 20));    // 512 KiB bf16 q (frag order)
    float*          Lt = (float*)((char*)d_ws + ((size_t)96 << 20) + (512 << 10)); // 256 KiB L table

    convert_kernel<<<8576, 256, 0, stream>>>(q, key, hist, qsw, kb, Lt);
    score_kernel<<<4096, 256, 0, stream>>>(qsw, kb, Lt, s8);
    select_kernel<<<BATCH, 256, 0, stream>>>(q, key, hist, vals, s8, out);
}

// Round 8
// 210.923 us; speedup vs baseline: 1.1823x; 1.0090x over previous
//
#include <hip/hip_runtime.h>

#define BATCH   1024
#define MSIZE   65536
#define KDIM    256
#define CHOOSEK 128
#define SELK    160        // suffix-count crossing target
#define BETA    1e-8f
#define ALPHA   0.5f
// u8 key = clamp((sim + log(hist+beta) + KOFF) * KSC). Monotone in score (log map, no exp).
// bytes>=128 ~ 1650/row (integral of Phi(-16*log(hmax/h)) over uniform hist) -> bit7
// prescreen keeps ~1400 words/row. Threshold byte ~165-175; bucket = 1/425 log-units
// vs bf16 screening error ~2.5e-4 -> wide superset margin.
#define KSC  425.0f
#define KOFF 7.2f

typedef short bf16x8 __attribute__((ext_vector_type(8)));
typedef float f32x4  __attribute__((ext_vector_type(4)));

__device__ inline unsigned int pack2bf(float a, float b) {   // RNE fp32->bf16 pair
    unsigned int ua = __float_as_uint(a);
    unsigned int ub = __float_as_uint(b);
    ua += 0x7fffu + ((ua >> 16) & 1u);
    ub += 0x7fffu + ((ub >> 16) & 1u);
    return (ua >> 16) | (ub & 0xffff0000u);
}

// async global->LDS, 16B/lane; LDS dest is wave-uniform base + lane*16 (must be linear in tid)
#define GLD16(g, l) __builtin_amdgcn_global_load_lds( \
    (const __attribute__((address_space(1))) unsigned int*)(g), \
    (__attribute__((address_space(3))) unsigned int*)(l), 16, 0, 0)

// -------------------------------------------------------------------------
// Kernel 0: one-time preprocessing.
//  blocks [0,8192):     key fp32 -> bf16 (kb)
//  blocks [8192,8320):  q fp32 -> bf16 in FRAGMENT order for the 256-row tile:
//      f = (((bt*4+wmg)*8+ks)*4+j)*64 + lane  (bt in [0,4), wmg in [0,4))
//      holds q row bt*256+wmg*64+j*16+(lane&15), cols ks*32+(lane>>4)*8 (16B)
//      -> score kernel reads each fragment as ONE coalesced dwordx4/wave.
//  blocks [8320,8576):  L[n] = (log(hist[n]+BETA)+KOFF)*KSC  (epilogue table)
// -------------------------------------------------------------------------
__global__ __launch_bounds__(256)
void convert_kernel(const float* __restrict__ q, const float* __restrict__ key,
                    const float* __restrict__ hist,
                    unsigned short* __restrict__ qs, unsigned short* __restrict__ kb,
                    float* __restrict__ Ltab)
{
    const int bid = blockIdx.x, tid = threadIdx.x;
    if (bid < 8192) {                       // key convert
        const int off = bid * 256 + tid;
        const float4* s4 = (const float4*)key;
        float4 a = s4[off * 2], b = s4[off * 2 + 1];
        ((uint4*)kb)[off] = make_uint4(pack2bf(a.x, a.y), pack2bf(a.z, a.w),
                                       pack2bf(b.x, b.y), pack2bf(b.z, b.w));
    } else if (bid < 8320) {                // q fragment-swizzle
        const int f = (bid - 8192) * 256 + tid;
        const int l = f & 63, j = (f >> 6) & 3, ks = (f >> 8) & 7;
        const int wmg = (f >> 11) & 3, bt = (f >> 13) & 3;
        const int r = bt * 256 + wmg * 64 + j * 16 + (l & 15);
        const int c = ks * 32 + (l >> 4) * 8;
        const float* src = q + (size_t)r * KDIM + c;
        float4 a = *(const float4*)src, b = *(const float4*)(src + 4);
        ((uint4*)qs)[f] = make_uint4(pack2bf(a.x, a.y), pack2bf(a.z, a.w),
                                     pack2bf(b.x, b.y), pack2bf(b.z, b.w));
    } else {                                // L table
        const int n = (bid - 8320) * 256 + tid;
        Ltab[n] = (logf(hist[n] + BETA) + KOFF) * KSC;
    }
}

// -------------------------------------------------------------------------
// Kernel 1: bf16 screening GEMM, 256x128 tile, 512 threads (8 waves, 4m x 2n),
// BK=32, K=256 -> 8 steps. Grid 2048 (half of r7): 2x MFMA per barrier.
//  - B (key) staged in 3-buffer LDS ring (24 KB), 1 GLD16/thread/stage,
//    counted vmcnt(1): one stage always in flight across the barrier.
//  - A (q) fragments: coalesced dwordx4 from the L2-resident fragment table,
//    SOFTWARE-PIPELINED ONE STEP AHEAD (qf double-buffer, static indices).
//    This fixes r5-r7's hidden serialization: per-step qf loads were OLDER
//    than the B prefetch in the vmcnt queue, so the compiler's pre-MFMA qf
//    wait forced the B prefetch to distance-1. One-step-ahead qf loads make
//    the pre-MFMA wait refer to last step's (long done) loads.
//  - T5 setprio around the MFMA cluster.
//  - Epilogue: byte = clamp(fma(sim, KSC, L[n])), packed dword stores.
// -------------------------------------------------------------------------
__global__ __launch_bounds__(512, 4)
void score_kernel(const unsigned short* __restrict__ qs,
                  const unsigned short* __restrict__ kb,
                  const float* __restrict__ Ltab,
                  unsigned char* __restrict__ s8)
{
    __shared__ __align__(16) unsigned short Bs[3][128 * 32];   // 3 x 8 KB
    const int tid = threadIdx.x;
    const int bid = blockIdx.x;
    const int bt = (bid >> 3) & 3;
    const int b0 = bt * 256;                               // batch tile (4)
    const int n0 = ((bid & 7) + ((bid >> 5) << 3)) * 128;  // memory tile (512), XCD-grouped
    const int lane = tid & 63, wave = tid >> 6;
    const int wm = (wave >> 1) * 64, wn = (wave & 1) * 64;
    const int l15 = lane & 15, l4 = lane >> 4;
    const int wmg = wave >> 1;

    f32x4 acc[4][4] = {};

    const int srow = tid >> 2;          // 0..127
    const int seg  = (tid & 3) * 8;
    const unsigned short* gB = kb + (size_t)(n0 + srow) * KDIM + seg;
    const int lofs = srow * 32 + seg;   // byte offset tid*16: linear per wave

    // per-wave fragment base: qw[(s*4+j)*64] is this lane's 16B A-fragment
    const bf16x8* qw = (const bf16x8*)qs + (size_t)((bt * 4 + wmg) * 32) * 64 + lane;

    bf16x8 qf[2][4];

#define STAGE_B(st) GLD16(gB + (st) * 32, &Bs[(st) % 3][lofs])

#define STEP(s, WN) do {                                                          \
    asm volatile("s_waitcnt vmcnt(" #WN ")" ::: "memory");                        \
    __builtin_amdgcn_s_barrier();                                                 \
    asm volatile("" ::: "memory");                                                \
    if ((s) < 7) {                                                                \
        _Pragma("unroll")                                                         \
        for (int j = 0; j < 4; ++j)                                               \
            qf[((s) + 1) & 1][j] = qw[(((s) + 1) * 4 + j) * 64];                  \
    }                                                                             \
    if ((s) + 2 < 8) STAGE_B((s) + 2);                                            \
    bf16x8 kf[4];                                                                 \
    _Pragma("unroll")                                                             \
    for (int i = 0; i < 4; ++i)                                                   \
        kf[i] = *(const bf16x8*)(&Bs[(s) % 3][(wn + i * 16 + l15) * 32 + l4 * 8]);\
    __builtin_amdgcn_s_setprio(1);                                                \
    _Pragma("unroll")                                                             \
    for (int i = 0; i < 4; ++i)                                                   \
        _Pragma("unroll")                                                         \
        for (int j = 0; j < 4; ++j)                                               \
            acc[i][j] = __builtin_amdgcn_mfma_f32_16x16x32_bf16(kf[i], qf[(s) & 1][j], acc[i][j], 0, 0, 0); \
    __builtin_amdgcn_s_setprio(0);                                                \
} while (0)

    // prologue: qf for step 0 FIRST (older than stages -> head vmcnt(1) covers
    // them + stage 0, leaves stage 1 in flight), then B stages 0,1.
#pragma unroll
    for (int j = 0; j < 4; ++j) qf[0][j] = qw[j * 64];
    STAGE_B(0); STAGE_B(1);

    STEP(0, 1); STEP(1, 1); STEP(2, 1); STEP(3, 1);
    STEP(4, 1); STEP(5, 1); STEP(6, 1); STEP(7, 0);

#undef STEP
#undef STAGE_B

    // epilogue: within acc[i][j]: mem = n0+wn+i*16+l4*4+reg, batch = b0+wm+j*16+l15
    float4 Lv[4];
#pragma unroll
    for (int i = 0; i < 4; ++i)
        Lv[i] = *(const float4*)&Ltab[n0 + wn + i * 16 + l4 * 4];
#pragma unroll
    for (int j = 0; j < 4; ++j) {
        const size_t row = (size_t)(b0 + wm + j * 16 + l15) * MSIZE;
#pragma unroll
        for (int i = 0; i < 4; ++i) {
            const float* lv = (const float*)&Lv[i];
            unsigned int pk = 0;
#pragma unroll
            for (int reg = 0; reg < 4; ++reg) {
                float x = fmaf(acc[i][j][reg], KSC, lv[reg]);
                x = fminf(fmaxf(x, 0.0f), 255.0f);
                pk |= (unsigned int)(int)x << (8 * reg);
            }
            *(unsigned int*)(s8 + row + (n0 + wn + i * 16 + l4 * 4)) = pk;
        }
    }
}

// -------------------------------------------------------------------------
// Kernel 2: per batch row.
//   pass 1: bit7-prescreened histogram + RECORD qualifying word indices
//           (wlist, ~1400/row, cap 2048). Exact full-histogram fallback.
//   single-wave shfl suffix-scan -> H.
//   pass 2: iterate ONLY wlist words (no second 64KB row stream). Fallback
//           to full stream if wlist overflowed or H < 128.
//   16-lane-group exact fp32 rescore; count-based exact top-128
//   (ties -> lower index); weighted sum.
// -------------------------------------------------------------------------
__global__ __launch_bounds__(256, 4)
void select_kernel(const float* __restrict__ q,
                   const float* __restrict__ key,
                   const float* __restrict__ hist,
                   const float* __restrict__ vals,
                   const unsigned char* __restrict__ s8,
                   float* __restrict__ out)
{
    const int b   = blockIdx.x;
    const int tid = threadIdx.x;

    __shared__ __align__(16) float qs[KDIM];
    __shared__ unsigned int hcnt[16 * 257];   // 16 replicated histograms
    __shared__ int   stot[256];
    __shared__ int   scal[3];                 // 0:H  1:ncand  2:nw
    __shared__ unsigned short wlist[2048];
    __shared__ int   cidx[1024];
    __shared__ float csc[1024], cjj[1024], cjv[1024];
    __shared__ float wred[8];

    qs[tid] = q[(size_t)b * KDIM + tid];
    const uint4* rowp = reinterpret_cast<const uint4*>(s8 + (size_t)b * MSIZE);
    const unsigned int* roww = reinterpret_cast<const unsigned int*>(rowp);
    const int rep = (tid & 15) * 257;

    // ---- threshold search: prescreened histogram + word-list, exact fallback ----
    int H = -1, nw = 0;
    int minb = 128;
    for (;;) {
        for (int i = tid; i < 16 * 257; i += 256) hcnt[i] = 0u;
        if (tid == 0) { scal[0] = -1; scal[1] = 0; scal[2] = 0; }
        __syncthreads();

        for (int i = 0; i < 16; ++i) {
            uint4 v = rowp[i * 256 + tid];
            unsigned int w[4] = {v.x, v.y, v.z, v.w};
#pragma unroll
            for (int k = 0; k < 4; ++k) {
                if (minb == 0 || (w[k] & 0x80808080u)) {
                    if (minb) {
                        int p = atomicAdd(&scal[2], 1);
                        if (p < 2048) wlist[p] = (unsigned short)((i * 256 + tid) * 4 + k);
                    }
#pragma unroll
                    for (int jj = 0; jj < 4; ++jj) {
                        int bb = (int)((w[k] >> (8 * jj)) & 0xffu);
                        if (bb >= minb) atomicAdd(&hcnt[rep + bb], 1u);
                    }
                }
            }
        }
        __syncthreads();
        { unsigned int t = 0;
#pragma unroll
          for (int k = 0; k < 16; ++k) t += hcnt[k * 257 + tid];
          stot[tid] = (int)t; }
        __syncthreads();

        // single-wave suffix scan over 256 bins; find crossing S[b]>=SELK>S[b+1]
        if (tid < 64) {
            const int l = tid;
            int t0 = stot[l * 4], t1 = stot[l * 4 + 1], t2 = stot[l * 4 + 2], t3 = stot[l * 4 + 3];
            int lsum = t0 + t1 + t2 + t3;
            int s = lsum;
#pragma unroll
            for (int off = 1; off < 64; off <<= 1) {
                int u = __shfl_down(s, off, 64);
                if (l + off < 64) s += u;
            }
            int A  = s - lsum;        // sum over lanes > l (== S[4l+4])
            int S3 = A + t3;
            int S2 = S3 + t2;
            int S1 = S2 + t1;
            int S0 = S1 + t0;
            if (S0 >= SELK && S1 < SELK) scal[0] = l * 4 + 0;
            if (S1 >= SELK && S2 < SELK) scal[0] = l * 4 + 1;
            if (S2 >= SELK && S3 < SELK) scal[0] = l * 4 + 2;
            if (S3 >= SELK && A  < SELK) scal[0] = l * 4 + 3;
        }
        __syncthreads();
        H = scal[0]; nw = scal[2];
        __syncthreads();              // all threads read H/nw before next-iter rewrites
        if (H >= 0) break;
        minb = 0;                     // threshold below 128: exact full histogram
    }

    // ---- pass 2: collect candidates (byte >= H) ----
    const unsigned int uH = (unsigned int)H;
    if (minb != 0 && nw <= 2048) {
        // word-list path: read only the ~1400 qualifying words
        for (int i = tid; i < nw; i += 256) {
            const int wi = (int)wlist[i];
            unsigned int w = roww[wi];
#pragma unroll
            for (int jj = 0; jj < 4; ++jj) {
                unsigned int bb = (w >> (8 * jj)) & 0xffu;
                if (bb >= uH) {
                    int p = atomicAdd(&scal[1], 1);
                    if (p < 1024) cidx[p] = wi * 4 + jj;
                }
            }
        }
    } else {
        // fallback: full row stream
        const bool pre = (H >= 128);
        for (int i = 0; i < 16; ++i) {
            uint4 v = rowp[i * 256 + tid];
            const int base = (i * 256 + tid) * 16;
            unsigned int w[4] = {v.x, v.y, v.z, v.w};
#pragma unroll
            for (int k = 0; k < 4; ++k) {
                if (!pre || (w[k] & 0x80808080u)) {
#pragma unroll
                    for (int jj = 0; jj < 4; ++jj) {
                        unsigned int bb = (w[k] >> (8 * jj)) & 0xffu;
                        if (bb >= uH) {
                            int p = atomicAdd(&scal[1], 1);
                            if (p < 1024) cidx[p] = base + 4 * k + jj;
                        }
                    }
                }
            }
        }
    }
    __syncthreads();
    const int ncand = min(scal[1], 1024);

    // ---- exact fp32 rescore: 16-lane groups, 4 candidates per wave in flight ----
    const int gid = tid >> 4, gl = tid & 15;
    const float4* q4 = (const float4*)qs;
    for (int i = gid; i < ncand; i += 16) {
        const int idx = cidx[i];
        const float4* kp = (const float4*)(key + (size_t)idx * KDIM);
        float p = 0.f;
#pragma unroll
        for (int u = 0; u < 4; ++u) {
            float4 kk = kp[gl * 4 + u];
            float4 qq = q4[gl * 4 + u];
            p += kk.x * qq.x + kk.y * qq.y + kk.z * qq.z + kk.w * qq.w;
        }
#pragma unroll
        for (int off = 1; off < 16; off <<= 1) p += __shfl_xor(p, off, 64);
        if (gl == 0) {
            float e = expf(p - 1.0f);
            float h = hist[idx];
            csc[i] = e * (h + BETA);
            float j = e * (ALPHA * h + BETA);
            cjj[i] = j;
            cjv[i] = j * vals[idx];
        }
    }
    __syncthreads();

    // ---- exact top-128 among candidates (count-based; ties -> lower index) ----
    const int wave = tid >> 6, lane = tid & 63;
    float pn = 0.f, pd = 0.f;
    for (int i = tid; i < ncand; i += 256) {
        float si = csc[i]; int ii = cidx[i]; int rank = 0;
        for (int t = 0; t < ncand; ++t) {
            float st = csc[t];
            rank += (st > si || (st == si && cidx[t] < ii)) ? 1 : 0;
        }
        if (rank < CHOOSEK) { pn += cjv[i]; pd += cjj[i]; }
    }
#pragma unroll
    for (int off = 32; off > 0; off >>= 1) {
        pn += __shfl_xor(pn, off, 64);
        pd += __shfl_xor(pd, off, 64);
    }
    if (lane == 0) { wred[wave] = pn; wred[4 + wave] = pd; }
    __syncthreads();
    if (tid == 0) {
        float n = wred[0] + wred[1] + wred[2] + wred[3];
        float d = wred[4] + wred[5] + wred[6] + wred[7];
        out[b] = n / d;
    }
}

// -------------------------------------------------------------------------
extern "C" void kernel_launch(void* const* d_in, const int* in_sizes, int n_in,
                              void* d_out, int out_size, void* d_ws, size_t ws_size,
                              hipStream_t stream)
{
    (void)in_sizes; (void)n_in; (void)out_size; (void)ws_size;
    const float* q    = (const float*)d_in[0];
    const float* key  = (const float*)d_in[1];
    const float* hist = (const float*)d_in[2];
    const float* vals = (const float*)d_in[3];
    float* out = (float*)d_out;

    // workspace layout (97.25 MiB total):
    unsigned char*  s8 = (unsigned char*)d_ws;                                   // 64 MiB u8 keys
    unsigned short* kb = (unsigned short*)((char*)d_ws + ((size_t)64 << 20));    // 32 MiB bf16 key
    unsigned short* qsw= (unsigned short*)((char*)d_ws + ((size_t)96 << 20));    // 512 KiB bf16 q (frag order)
    float*          Lt = (float*)((char*)d_ws + ((size_t)96 << 20) + (512 << 10)); // 256 KiB L table

    convert_kernel<<<8576, 256, 0, stream>>>(q, key, hist, qsw, kb, Lt);
    score_kernel<<<2048, 512, 0, stream>>>(qsw, kb, Lt, s8);
    select_kernel<<<BATCH, 256, 0, stream>>>(q, key, hist, vals, s8, out);
}